// Round 2
// baseline (1421.423 us; speedup 1.0000x reference)
//
#include <hip/hip_runtime.h>
#include <math.h>

#define NB 8
#define NN 4096
#define NDIM 512
#define NH 8
#define NDH 64
#define QKVC 1536
#define NROWS (NB * NN)
#define EPSF 1e-5f
#define INV_N (1.0f / 4096.0f)
// log2(10000)/16
#define L2_10K_16 0.8304820237218406f

// ---------------------------------------------------------------------------
// GEMM: C[m][n] = sum_k A[m][k] * Bm[n][k] (+ bias[n])
// A has leading dimension lda (>= K). Tiles: 64x64, BK=16, 256 threads,
// 4x4 micro-tile per thread. LDS k-major so inner reads are float4.
// ---------------------------------------------------------------------------
__global__ __launch_bounds__(256)
void gemm_bt_kernel(const float* __restrict__ A, const float* __restrict__ Bm,
                    const float* __restrict__ bias, float* __restrict__ C,
                    int M, int Nc, int K, int lda)
{
    __shared__ float As[16][64];
    __shared__ float Bs[16][64];
    const int tx = threadIdx.x & 15;
    const int ty = threadIdx.x >> 4;
    const int m0 = blockIdx.y * 64;
    const int n0 = blockIdx.x * 64;
    const int lrow = threadIdx.x >> 2;  // 0..63
    const int lq   = threadIdx.x & 3;   // 0..3

    float acc[4][4] = {{0.0f}};

    const float* Aptr = A  + (size_t)(m0 + lrow) * lda + lq * 4;
    const float* Bptr = Bm + (size_t)(n0 + lrow) * K + lq * 4;

    float4 av = *(const float4*)(Aptr);
    float4 bv = *(const float4*)(Bptr);

    for (int kt = 0; kt < K; kt += 16) {
        __syncthreads();
        As[lq*4+0][lrow] = av.x; As[lq*4+1][lrow] = av.y;
        As[lq*4+2][lrow] = av.z; As[lq*4+3][lrow] = av.w;
        Bs[lq*4+0][lrow] = bv.x; Bs[lq*4+1][lrow] = bv.y;
        Bs[lq*4+2][lrow] = bv.z; Bs[lq*4+3][lrow] = bv.w;
        __syncthreads();
        if (kt + 16 < K) {
            av = *(const float4*)(Aptr + kt + 16);
            bv = *(const float4*)(Bptr + kt + 16);
        }
        #pragma unroll
        for (int k = 0; k < 16; ++k) {
            float4 a = *(const float4*)&As[k][ty * 4];
            float4 b = *(const float4*)&Bs[k][tx * 4];
            acc[0][0] += a.x*b.x; acc[0][1] += a.x*b.y; acc[0][2] += a.x*b.z; acc[0][3] += a.x*b.w;
            acc[1][0] += a.y*b.x; acc[1][1] += a.y*b.y; acc[1][2] += a.y*b.z; acc[1][3] += a.y*b.w;
            acc[2][0] += a.z*b.x; acc[2][1] += a.z*b.y; acc[2][2] += a.z*b.z; acc[2][3] += a.z*b.w;
            acc[3][0] += a.w*b.x; acc[3][1] += a.w*b.y; acc[3][2] += a.w*b.z; acc[3][3] += a.w*b.w;
        }
    }

    float4 bb = make_float4(0.f, 0.f, 0.f, 0.f);
    if (bias != nullptr) {
        bb = *(const float4*)(bias + n0 + tx * 4);
    }
    #pragma unroll
    for (int i = 0; i < 4; ++i) {
        float4 o = make_float4(acc[i][0] + bb.x, acc[i][1] + bb.y,
                               acc[i][2] + bb.z, acc[i][3] + bb.w);
        *(float4*)(C + (size_t)(m0 + ty * 4 + i) * Nc + n0 + tx * 4) = o;
    }
}

// ---------------------------------------------------------------------------
// LN(k), LN(v), RoPE2D(q, k) in-place on qkv. One 16-lane group per (b,n,h).
// Each lane holds elems d = 4g..4g+3 of the 64-dim head vector.
// RoPE pairing: within each 32-half, (i, i+16) -> partner lane = g ^ 4.
// ---------------------------------------------------------------------------
__global__ __launch_bounds__(256)
void ln_rope_kernel(float* __restrict__ qkv, const float* __restrict__ pos,
                    const float* __restrict__ gk, const float* __restrict__ bk,
                    const float* __restrict__ gv, const float* __restrict__ bvv)
{
    const int tid = blockIdx.x * 256 + threadIdx.x;
    const int gid = tid >> 4;       // (b*N+n)*H + h
    const int g   = tid & 15;
    const int h   = gid & 7;
    const int row = gid >> 3;       // b*N + n
    const size_t base = (size_t)row * QKVC + h * NDH + g * 4;

    float4 q = *(float4*)(qkv + base);
    float4 k = *(float4*)(qkv + base + 512);
    float4 v = *(float4*)(qkv + base + 1024);

    // group reductions (16 lanes) for layernorm of k and v
    float sk  = k.x + k.y + k.z + k.w;
    float ssk = k.x*k.x + k.y*k.y + k.z*k.z + k.w*k.w;
    float sv  = v.x + v.y + v.z + v.w;
    float ssv = v.x*v.x + v.y*v.y + v.z*v.z + v.w*v.w;
    #pragma unroll
    for (int w = 1; w < 16; w <<= 1) {
        sk  += __shfl_xor(sk,  w, 64);
        ssk += __shfl_xor(ssk, w, 64);
        sv  += __shfl_xor(sv,  w, 64);
        ssv += __shfl_xor(ssv, w, 64);
    }
    const float muk = sk * (1.0f / 64.0f);
    const float rsk = rsqrtf(ssk * (1.0f / 64.0f) - muk * muk + EPSF);
    const float muv = sv * (1.0f / 64.0f);
    const float rsv = rsqrtf(ssv * (1.0f / 64.0f) - muv * muv + EPSF);

    const float4 Gk = *(const float4*)(gk + g * 4);
    const float4 Bk = *(const float4*)(bk + g * 4);
    const float4 Gv = *(const float4*)(gv + g * 4);
    const float4 Bv = *(const float4*)(bvv + g * 4);

    k.x = (k.x - muk) * rsk * Gk.x + Bk.x;
    k.y = (k.y - muk) * rsk * Gk.y + Bk.y;
    k.z = (k.z - muk) * rsk * Gk.z + Bk.z;
    k.w = (k.w - muk) * rsk * Gk.w + Bk.w;
    v.x = (v.x - muv) * rsv * Gv.x + Bv.x;
    v.y = (v.y - muv) * rsv * Gv.y + Bv.y;
    v.z = (v.z - muv) * rsv * Gv.z + Bv.z;
    v.w = (v.w - muv) * rsv * Gv.w + Bv.w;

    // RoPE 2D: dims 0..31 use pos.x, 32..63 use pos.y; theta = coord*64*invf[i%16]
    const float2 p = *(const float2*)(pos + (size_t)row * 2);
    const float coord = ((g & 8) ? p.y : p.x) * 64.0f;
    const int j0 = (g & 3) * 4;
    float cs[4], sn[4];
    #pragma unroll
    for (int c = 0; c < 4; ++c) {
        const float th = coord * exp2f(-(float)(j0 + c) * L2_10K_16);
        sincosf(th, &sn[c], &cs[c]);
    }
    // i<16 within half: out = t*c - partner*s ; i>=16: out = t*c + partner*s
    const float sgn = (g & 4) ? 1.0f : -1.0f;

    float4 qp, kp;
    qp.x = __shfl_xor(q.x, 4, 64); qp.y = __shfl_xor(q.y, 4, 64);
    qp.z = __shfl_xor(q.z, 4, 64); qp.w = __shfl_xor(q.w, 4, 64);
    kp.x = __shfl_xor(k.x, 4, 64); kp.y = __shfl_xor(k.y, 4, 64);
    kp.z = __shfl_xor(k.z, 4, 64); kp.w = __shfl_xor(k.w, 4, 64);

    q.x = q.x * cs[0] + sgn * qp.x * sn[0];
    q.y = q.y * cs[1] + sgn * qp.y * sn[1];
    q.z = q.z * cs[2] + sgn * qp.z * sn[2];
    q.w = q.w * cs[3] + sgn * qp.w * sn[3];
    k.x = k.x * cs[0] + sgn * kp.x * sn[0];
    k.y = k.y * cs[1] + sgn * kp.y * sn[1];
    k.z = k.z * cs[2] + sgn * kp.z * sn[2];
    k.w = k.w * cs[3] + sgn * kp.w * sn[3];

    *(float4*)(qkv + base)        = q;
    *(float4*)(qkv + base + 512)  = k;
    *(float4*)(qkv + base + 1024) = v;
}

// ---------------------------------------------------------------------------
// dots[b][h][d][e] = sum_n k[b,h,n,d] * v[b,h,n,e]   (atomicAdd across chunks)
// Block: (chunk of 256 n, h, b). Each thread owns a 4x4 (d,e) block.
// ---------------------------------------------------------------------------
__global__ __launch_bounds__(256)
void dots_kernel(const float* __restrict__ qkv, float* __restrict__ dots)
{
    __shared__ float ks[8][64];
    __shared__ float vs[8][64];
    const int b = blockIdx.z, h = blockIdx.y;
    const int n0 = blockIdx.x * 256;
    const int t = threadIdx.x;
    const int half = t >> 7;           // 0: load k, 1: load v
    const int idx  = t & 127;
    const int lr = idx >> 4, lq4 = idx & 15;
    const int d0 = (t >> 4) * 4;
    const int e0 = (t & 15) * 4;

    float acc[4][4] = {{0.0f}};
    const size_t gbase = (size_t)(b * NN + n0) * QKVC + (half ? 1024 : 512)
                       + h * NDH + lq4 * 4;

    float4 val = *(const float4*)(qkv + gbase + (size_t)lr * QKVC);
    for (int s = 0; s < 32; ++s) {
        __syncthreads();
        float (*dst)[64] = half ? vs : ks;
        *(float4*)&dst[lr][lq4 * 4] = val;
        __syncthreads();
        if (s + 1 < 32)
            val = *(const float4*)(qkv + gbase + (size_t)((s + 1) * 8 + lr) * QKVC);
        #pragma unroll
        for (int r = 0; r < 8; ++r) {
            float4 kd = *(float4*)&ks[r][d0];
            float4 ve = *(float4*)&vs[r][e0];
            acc[0][0] += kd.x*ve.x; acc[0][1] += kd.x*ve.y; acc[0][2] += kd.x*ve.z; acc[0][3] += kd.x*ve.w;
            acc[1][0] += kd.y*ve.x; acc[1][1] += kd.y*ve.y; acc[1][2] += kd.y*ve.z; acc[1][3] += kd.y*ve.w;
            acc[2][0] += kd.z*ve.x; acc[2][1] += kd.z*ve.y; acc[2][2] += kd.z*ve.z; acc[2][3] += kd.z*ve.w;
            acc[3][0] += kd.w*ve.x; acc[3][1] += kd.w*ve.y; acc[3][2] += kd.w*ve.z; acc[3][3] += kd.w*ve.w;
        }
    }
    float* dp = dots + ((size_t)(b * NH + h) * 64 + d0) * 64 + e0;
    #pragma unroll
    for (int i = 0; i < 4; ++i)
        #pragma unroll
        for (int j = 0; j < 4; ++j)
            atomicAdd(dp + i * 64 + j, acc[i][j]);
}

// ---------------------------------------------------------------------------
// out_h[b][n][h*64+e] = (1/N) * sum_d q[b,n,h,d] * dots[b][h][d][e]
// Writes out_h IN PLACE over the q columns of qkv (stride QKVC). Safe:
// each block reads its q sub-block fully into LDS (then __syncthreads)
// before overwriting it, and (n-tile, h) regions are disjoint across blocks.
// Block: (tile of 128 n, h, b). dots tile + q tile staged in LDS.
// ---------------------------------------------------------------------------
__global__ __launch_bounds__(256)
void qdots_kernel(float* __restrict__ qkv, const float* __restrict__ dots)
{
    __shared__ float ds[64][64];
    __shared__ float qs[128][65];
    const int b = blockIdx.z, h = blockIdx.y;
    const int n0 = blockIdx.x * 128;
    const int t = threadIdx.x;

    const float4* dsrc = (const float4*)(dots + (size_t)(b * NH + h) * 4096);
    float4* ddst = (float4*)&ds[0][0];
    #pragma unroll
    for (int i = 0; i < 4; ++i)
        ddst[t + i * 256] = dsrc[t + i * 256];

    #pragma unroll
    for (int i = 0; i < 8; ++i) {
        const int idx = i * 256 + t;
        const int r = idx >> 4, q4 = idx & 15;
        float4 qv = *(const float4*)(qkv + (size_t)(b * NN + n0 + r) * QKVC + h * NDH + q4 * 4);
        qs[r][q4 * 4 + 0] = qv.x; qs[r][q4 * 4 + 1] = qv.y;
        qs[r][q4 * 4 + 2] = qv.z; qs[r][q4 * 4 + 3] = qv.w;
    }
    __syncthreads();

    const int eq = t & 15;   // e block: eq*4 .. eq*4+3
    const int rg = t >> 4;   // rows rg*8 .. rg*8+7
    float acc[8][4] = {{0.0f}};
    for (int d = 0; d < 64; ++d) {
        float4 dv = *(float4*)&ds[d][eq * 4];
        #pragma unroll
        for (int r = 0; r < 8; ++r) {
            const float qv = qs[rg * 8 + r][d];
            acc[r][0] += qv * dv.x; acc[r][1] += qv * dv.y;
            acc[r][2] += qv * dv.z; acc[r][3] += qv * dv.w;
        }
    }
    #pragma unroll
    for (int r = 0; r < 8; ++r) {
        float4 o = make_float4(acc[r][0] * INV_N, acc[r][1] * INV_N,
                               acc[r][2] * INV_N, acc[r][3] * INV_N);
        *(float4*)(qkv + (size_t)(b * NN + n0 + rg * 8 + r) * QKVC + h * NDH + eq * 4) = o;
    }
}

// ---------------------------------------------------------------------------
extern "C" void kernel_launch(void* const* d_in, const int* in_sizes, int n_in,
                              void* d_out, int out_size, void* d_ws, size_t ws_size,
                              hipStream_t stream)
{
    const float* x    = (const float*)d_in[0];
    const float* pos  = (const float*)d_in[1];
    const float* Wqkv = (const float*)d_in[2];
    const float* gk   = (const float*)d_in[3];
    const float* bk   = (const float*)d_in[4];
    const float* gv   = (const float*)d_in[5];
    const float* bv   = (const float*)d_in[6];
    const float* Wout = (const float*)d_in[7];
    const float* bout = (const float*)d_in[8];
    float* out = (float*)d_out;

    // ws layout: dots (1 MB) then qkv (192 MB). out_h overlays qkv's q cols.
    float* dots = (float*)d_ws;                            // 8*8*64*64 fp32
    float* qkv  = dots + (size_t)NB * NH * 64 * 64;        // 32768*1536 fp32

    hipMemsetAsync(dots, 0, (size_t)NB * NH * 64 * 64 * sizeof(float), stream);

    dim3 blk(256);
    // 1) qkv = x @ Wqkv^T
    gemm_bt_kernel<<<dim3(QKVC / 64, NROWS / 64), blk, 0, stream>>>(
        x, Wqkv, nullptr, qkv, NROWS, QKVC, NDIM, NDIM);
    // 2) LN(k), LN(v), RoPE(q,k) in-place
    ln_rope_kernel<<<dim3((NROWS * NH * 16) / 256), blk, 0, stream>>>(
        qkv, pos, gk, bk, gv, bv);
    // 3) dots = k^T v per (b,h)
    dots_kernel<<<dim3(NN / 256, NH, NB), blk, 0, stream>>>(qkv, dots);
    // 4) out_h = q @ dots / N  (written over q columns of qkv, stride QKVC)
    qdots_kernel<<<dim3(NN / 128, NH, NB), blk, 0, stream>>>(qkv, dots);
    // 5) out = out_h @ Wout^T + bout   (A = qkv q-columns, lda = QKVC)
    gemm_bt_kernel<<<dim3(NDIM / 64, NROWS / 64), blk, 0, stream>>>(
        qkv, Wout, bout, out, NROWS, NDIM, NDIM, QKVC);
}

// Round 3
// 424.806 us; speedup vs baseline: 3.3461x; 3.3461x over previous
//
#include <hip/hip_runtime.h>
#include <math.h>

#define NB 8
#define NN 4096
#define NDIM 512
#define NH 8
#define NDH 64
#define QKVC 1536
#define NROWS (NB * NN)
#define EPSF 1e-5f
#define INV_N (1.0f / 4096.0f)
// log2(10000)/16
#define L2_10K_16 0.8304820237218406f

typedef __bf16 bf16x8_t __attribute__((ext_vector_type(8)));
typedef float f32x4_t __attribute__((ext_vector_type(4)));

__device__ inline unsigned short f2bf(float f) {
    unsigned u = __builtin_bit_cast(unsigned, f);
    u += 0x7fff + ((u >> 16) & 1);          // round-to-nearest-even
    return (unsigned short)(u >> 16);
}

// async global->LDS, 16B per lane; LDS dest = wave-uniform base + lane*16
#define GLOAD_LDS16(g, s) __builtin_amdgcn_global_load_lds(                    \
    (const __attribute__((address_space(1))) void*)(g),                        \
    (__attribute__((address_space(3))) void*)(s), 16, 0, 0)

// ---------------------------------------------------------------------------
// fp32 -> bf16 convert, 8 elems/thread. n must be multiple of 8.
// ---------------------------------------------------------------------------
__global__ __launch_bounds__(256)
void cvt_bf16_kernel(const float* __restrict__ s, unsigned short* __restrict__ d, int n)
{
    const int i = (blockIdx.x * 256 + threadIdx.x) * 8;
    if (i >= n) return;
    float4 a = *(const float4*)(s + i);
    float4 b = *(const float4*)(s + i + 4);
    ushort4 lo, hi;
    lo.x = f2bf(a.x); lo.y = f2bf(a.y); lo.z = f2bf(a.z); lo.w = f2bf(a.w);
    hi.x = f2bf(b.x); hi.y = f2bf(b.y); hi.z = f2bf(b.z); hi.w = f2bf(b.w);
    *(ushort4*)(d + i)     = lo;
    *(ushort4*)(d + i + 4) = hi;
}

// ---------------------------------------------------------------------------
// MFMA GEMM: C[m][n] = sum_k A[m][k]*Bm[n][k] (+bias[n]), A,Bm bf16 row-major
// (lda = ldb = K), C fp32. 128x128 tile, BK=32, 256 thr = 4 waves, each wave
// a 4x4 grid of 16x16x32 MFMAs. m97 structure: global_load_lds dwordx4
// staging into unpadded row-major LDS, 2 barriers per K-step.
// ---------------------------------------------------------------------------
__global__ __launch_bounds__(256)
void gemm_bt_mfma(const unsigned short* __restrict__ A,
                  const unsigned short* __restrict__ Bm,
                  const float* __restrict__ bias, float* __restrict__ C,
                  int M, int Nc, int K)
{
    __shared__ unsigned short As[128 * 32];
    __shared__ unsigned short Bs[128 * 32];
    const int t    = threadIdx.x;
    const int wave = t >> 6;
    const int lane = t & 63;
    const int m0 = blockIdx.y * 128;
    const int n0 = blockIdx.x * 128;
    const int wm = (wave >> 1) * 64;    // wave's m-offset in tile
    const int wn = (wave & 1) * 64;     // wave's n-offset in tile

    f32x4_t acc[4][4] = {};

    // staging: wave stages A rows [wave*32, wave*32+32) and same B rows.
    // instr i (i=0,1): 16 rows; lane l -> row i*16 + (l>>2), kchunk (l&3)*8.
    const int srow = wave * 32 + (lane >> 2);
    const int scol = (lane & 3) * 8;
    const unsigned short* Ag = A + (size_t)(m0 + srow) * K + scol;
    const unsigned short* Bg = Bm + (size_t)(n0 + srow) * K + scol;
    unsigned short* sA = As + wave * 1024;   // wave's 2KB region (32 rows)
    unsigned short* sB = Bs + wave * 1024;

    // fragment addressing
    const int fr = lane & 15;           // row within 16-tile
    const int fq = (lane >> 4) * 8;     // k-offset within BK=32

    for (int kt = 0; kt < K; kt += 32) {
        __syncthreads();                 // previous tile's readers done
        GLOAD_LDS16(Ag + kt,          sA);
        GLOAD_LDS16(Ag + kt + 16 * K, sA + 512);
        GLOAD_LDS16(Bg + kt,          sB);
        GLOAD_LDS16(Bg + kt + 16 * K, sB + 512);
        __syncthreads();                 // vmcnt(0) drain + barrier

        bf16x8_t af[4], bf[4];
        #pragma unroll
        for (int i = 0; i < 4; ++i) {
            af[i] = *(const bf16x8_t*)&As[(wm + i * 16 + fr) * 32 + fq];
            bf[i] = *(const bf16x8_t*)&Bs[(wn + i * 16 + fr) * 32 + fq];
        }
        #pragma unroll
        for (int i = 0; i < 4; ++i)
            #pragma unroll
            for (int j = 0; j < 4; ++j)
                acc[i][j] = __builtin_amdgcn_mfma_f32_16x16x32_bf16(
                    af[i], bf[j], acc[i][j], 0, 0, 0);
    }

    // epilogue: lane l, reg r -> row (l>>4)*4+r, col l&15 of each 16x16 tile
    const int crow = (lane >> 4) * 4;
    const int ccol = lane & 15;
    #pragma unroll
    for (int j = 0; j < 4; ++j) {
        const int cn = n0 + wn + j * 16 + ccol;
        const float bb = bias ? bias[cn] : 0.0f;
        #pragma unroll
        for (int i = 0; i < 4; ++i) {
            float* cp = C + (size_t)(m0 + wm + i * 16 + crow) * Nc + cn;
            #pragma unroll
            for (int r = 0; r < 4; ++r)
                cp[(size_t)r * Nc] = acc[i][j][r] + bb;
        }
    }
}

// ---------------------------------------------------------------------------
// LN(k), LN(v), RoPE2D(q, k) in-place on fp32 qkv. One 16-lane group per
// (b,n,h); lane holds elems d = 4g..4g+3. RoPE pair (i, i+16) -> shfl_xor 4.
// ---------------------------------------------------------------------------
__global__ __launch_bounds__(256)
void ln_rope_kernel(float* __restrict__ qkv, const float* __restrict__ pos,
                    const float* __restrict__ gk, const float* __restrict__ bk,
                    const float* __restrict__ gv, const float* __restrict__ bvv)
{
    const int tid = blockIdx.x * 256 + threadIdx.x;
    const int gid = tid >> 4;       // (b*N+n)*H + h
    const int g   = tid & 15;
    const int h   = gid & 7;
    const int row = gid >> 3;       // b*N + n
    const size_t base = (size_t)row * QKVC + h * NDH + g * 4;

    float4 q = *(float4*)(qkv + base);
    float4 k = *(float4*)(qkv + base + 512);
    float4 v = *(float4*)(qkv + base + 1024);

    float sk  = k.x + k.y + k.z + k.w;
    float ssk = k.x*k.x + k.y*k.y + k.z*k.z + k.w*k.w;
    float sv  = v.x + v.y + v.z + v.w;
    float ssv = v.x*v.x + v.y*v.y + v.z*v.z + v.w*v.w;
    #pragma unroll
    for (int w = 1; w < 16; w <<= 1) {
        sk  += __shfl_xor(sk,  w, 64);
        ssk += __shfl_xor(ssk, w, 64);
        sv  += __shfl_xor(sv,  w, 64);
        ssv += __shfl_xor(ssv, w, 64);
    }
    const float muk = sk * (1.0f / 64.0f);
    const float rsk = rsqrtf(ssk * (1.0f / 64.0f) - muk * muk + EPSF);
    const float muv = sv * (1.0f / 64.0f);
    const float rsv = rsqrtf(ssv * (1.0f / 64.0f) - muv * muv + EPSF);

    const float4 Gk = *(const float4*)(gk + g * 4);
    const float4 Bk = *(const float4*)(bk + g * 4);
    const float4 Gv = *(const float4*)(gv + g * 4);
    const float4 Bv = *(const float4*)(bvv + g * 4);

    k.x = (k.x - muk) * rsk * Gk.x + Bk.x;
    k.y = (k.y - muk) * rsk * Gk.y + Bk.y;
    k.z = (k.z - muk) * rsk * Gk.z + Bk.z;
    k.w = (k.w - muk) * rsk * Gk.w + Bk.w;
    v.x = (v.x - muv) * rsv * Gv.x + Bv.x;
    v.y = (v.y - muv) * rsv * Gv.y + Bv.y;
    v.z = (v.z - muv) * rsv * Gv.z + Bv.z;
    v.w = (v.w - muv) * rsv * Gv.w + Bv.w;

    const float2 p = *(const float2*)(pos + (size_t)row * 2);
    const float coord = ((g & 8) ? p.y : p.x) * 64.0f;
    const int j0 = (g & 3) * 4;
    float cs[4], sn[4];
    #pragma unroll
    for (int c = 0; c < 4; ++c) {
        const float th = coord * exp2f(-(float)(j0 + c) * L2_10K_16);
        sincosf(th, &sn[c], &cs[c]);
    }
    const float sgn = (g & 4) ? 1.0f : -1.0f;

    float4 qp, kp;
    qp.x = __shfl_xor(q.x, 4, 64); qp.y = __shfl_xor(q.y, 4, 64);
    qp.z = __shfl_xor(q.z, 4, 64); qp.w = __shfl_xor(q.w, 4, 64);
    kp.x = __shfl_xor(k.x, 4, 64); kp.y = __shfl_xor(k.y, 4, 64);
    kp.z = __shfl_xor(k.z, 4, 64); kp.w = __shfl_xor(k.w, 4, 64);

    q.x = q.x * cs[0] + sgn * qp.x * sn[0];
    q.y = q.y * cs[1] + sgn * qp.y * sn[1];
    q.z = q.z * cs[2] + sgn * qp.z * sn[2];
    q.w = q.w * cs[3] + sgn * qp.w * sn[3];
    k.x = k.x * cs[0] + sgn * kp.x * sn[0];
    k.y = k.y * cs[1] + sgn * kp.y * sn[1];
    k.z = k.z * cs[2] + sgn * kp.z * sn[2];
    k.w = k.w * cs[3] + sgn * kp.w * sn[3];

    *(float4*)(qkv + base)        = q;
    *(float4*)(qkv + base + 512)  = k;
    *(float4*)(qkv + base + 1024) = v;
}

// ---------------------------------------------------------------------------
// dots[b][h][d][e] = sum_n k[b,h,n,d] * v[b,h,n,e]   (atomicAdd across chunks)
// ---------------------------------------------------------------------------
__global__ __launch_bounds__(256)
void dots_kernel(const float* __restrict__ qkv, float* __restrict__ dots)
{
    __shared__ float ks[8][64];
    __shared__ float vs[8][64];
    const int b = blockIdx.z, h = blockIdx.y;
    const int n0 = blockIdx.x * 256;
    const int t = threadIdx.x;
    const int half = t >> 7;           // 0: load k, 1: load v
    const int idx  = t & 127;
    const int lr = idx >> 4, lq4 = idx & 15;
    const int d0 = (t >> 4) * 4;
    const int e0 = (t & 15) * 4;

    float acc[4][4] = {{0.0f}};
    const size_t gbase = (size_t)(b * NN + n0) * QKVC + (half ? 1024 : 512)
                       + h * NDH + lq4 * 4;

    float4 val = *(const float4*)(qkv + gbase + (size_t)lr * QKVC);
    for (int s = 0; s < 32; ++s) {
        __syncthreads();
        float (*dst)[64] = half ? vs : ks;
        *(float4*)&dst[lr][lq4 * 4] = val;
        __syncthreads();
        if (s + 1 < 32)
            val = *(const float4*)(qkv + gbase + (size_t)((s + 1) * 8 + lr) * QKVC);
        #pragma unroll
        for (int r = 0; r < 8; ++r) {
            float4 kd = *(float4*)&ks[r][d0];
            float4 ve = *(float4*)&vs[r][e0];
            acc[0][0] += kd.x*ve.x; acc[0][1] += kd.x*ve.y; acc[0][2] += kd.x*ve.z; acc[0][3] += kd.x*ve.w;
            acc[1][0] += kd.y*ve.x; acc[1][1] += kd.y*ve.y; acc[1][2] += kd.y*ve.z; acc[1][3] += kd.y*ve.w;
            acc[2][0] += kd.z*ve.x; acc[2][1] += kd.z*ve.y; acc[2][2] += kd.z*ve.z; acc[2][3] += kd.z*ve.w;
            acc[3][0] += kd.w*ve.x; acc[3][1] += kd.w*ve.y; acc[3][2] += kd.w*ve.z; acc[3][3] += kd.w*ve.w;
        }
    }
    float* dp = dots + ((size_t)(b * NH + h) * 64 + d0) * 64 + e0;
    #pragma unroll
    for (int i = 0; i < 4; ++i)
        #pragma unroll
        for (int j = 0; j < 4; ++j)
            atomicAdd(dp + i * 64 + j, acc[i][j]);
}

// ---------------------------------------------------------------------------
// out_hb[b][n][h*64+e] = bf16( (1/N) * sum_d q[b,n,h,d] * dots[b][h][d][e] )
// ---------------------------------------------------------------------------
__global__ __launch_bounds__(256)
void qdots_kernel(const float* __restrict__ qkv, const float* __restrict__ dots,
                  unsigned short* __restrict__ out_hb)
{
    __shared__ float ds[64][64];
    __shared__ float qs[128][65];
    const int b = blockIdx.z, h = blockIdx.y;
    const int n0 = blockIdx.x * 128;
    const int t = threadIdx.x;

    const float4* dsrc = (const float4*)(dots + (size_t)(b * NH + h) * 4096);
    float4* ddst = (float4*)&ds[0][0];
    #pragma unroll
    for (int i = 0; i < 4; ++i)
        ddst[t + i * 256] = dsrc[t + i * 256];

    #pragma unroll
    for (int i = 0; i < 8; ++i) {
        const int idx = i * 256 + t;
        const int r = idx >> 4, q4 = idx & 15;
        float4 qv = *(const float4*)(qkv + (size_t)(b * NN + n0 + r) * QKVC + h * NDH + q4 * 4);
        qs[r][q4 * 4 + 0] = qv.x; qs[r][q4 * 4 + 1] = qv.y;
        qs[r][q4 * 4 + 2] = qv.z; qs[r][q4 * 4 + 3] = qv.w;
    }
    __syncthreads();

    const int eq = t & 15;
    const int rg = t >> 4;
    float acc[8][4] = {{0.0f}};
    for (int d = 0; d < 64; ++d) {
        float4 dv = *(float4*)&ds[d][eq * 4];
        #pragma unroll
        for (int r = 0; r < 8; ++r) {
            const float qv = qs[rg * 8 + r][d];
            acc[r][0] += qv * dv.x; acc[r][1] += qv * dv.y;
            acc[r][2] += qv * dv.z; acc[r][3] += qv * dv.w;
        }
    }
    #pragma unroll
    for (int r = 0; r < 8; ++r) {
        ushort4 o;
        o.x = f2bf(acc[r][0] * INV_N); o.y = f2bf(acc[r][1] * INV_N);
        o.z = f2bf(acc[r][2] * INV_N); o.w = f2bf(acc[r][3] * INV_N);
        *(ushort4*)(out_hb + (size_t)(b * NN + n0 + rg * 8 + r) * NDIM + h * NDH + eq * 4) = o;
    }
}

// ---------------------------------------------------------------------------
extern "C" void kernel_launch(void* const* d_in, const int* in_sizes, int n_in,
                              void* d_out, int out_size, void* d_ws, size_t ws_size,
                              hipStream_t stream)
{
    const float* x    = (const float*)d_in[0];
    const float* pos  = (const float*)d_in[1];
    const float* Wqkv = (const float*)d_in[2];
    const float* gk   = (const float*)d_in[3];
    const float* bk   = (const float*)d_in[4];
    const float* gv   = (const float*)d_in[5];
    const float* bv   = (const float*)d_in[6];
    const float* Wout = (const float*)d_in[7];
    const float* bout = (const float*)d_in[8];
    float* out = (float*)d_out;

    // ws: dots(1MiB) | qkv fp32(192MiB) | xb/out_hb shared(32MiB) | Wb(2MiB)
    float* dots = (float*)d_ws;
    float* qkv  = dots + (size_t)NB * NH * 64 * 64;
    unsigned short* xb     = (unsigned short*)(qkv + (size_t)NROWS * QKVC);
    unsigned short* out_hb = xb;                       // xb dead before qdots
    unsigned short* Wqkvb  = xb + (size_t)NROWS * NDIM;
    unsigned short* Woutb  = Wqkvb + (size_t)QKVC * NDIM;

    hipMemsetAsync(dots, 0, (size_t)NB * NH * 64 * 64 * sizeof(float), stream);

    dim3 blk(256);
    // 0) fp32 -> bf16 converts
    cvt_bf16_kernel<<<dim3(NROWS * NDIM / 2048), blk, 0, stream>>>(x, xb, NROWS * NDIM);
    cvt_bf16_kernel<<<dim3(QKVC * NDIM / 2048), blk, 0, stream>>>(Wqkv, Wqkvb, QKVC * NDIM);
    cvt_bf16_kernel<<<dim3(NDIM * NDIM / 2048), blk, 0, stream>>>(Wout, Woutb, NDIM * NDIM);
    // 1) qkv = x @ Wqkv^T   (bf16 MFMA, fp32 out)
    gemm_bt_mfma<<<dim3(QKVC / 128, NROWS / 128), blk, 0, stream>>>(
        xb, Wqkvb, nullptr, qkv, NROWS, QKVC, NDIM);
    // 2) LN(k), LN(v), RoPE(q,k) in-place
    ln_rope_kernel<<<dim3((NROWS * NH * 16) / 256), blk, 0, stream>>>(
        qkv, pos, gk, bk, gv, bv);
    // 3) dots = k^T v per (b,h)
    dots_kernel<<<dim3(NN / 256, NH, NB), blk, 0, stream>>>(qkv, dots);
    // 4) out_hb = bf16(q @ dots / N)
    qdots_kernel<<<dim3(NN / 128, NH, NB), blk, 0, stream>>>(qkv, dots, out_hb);
    // 5) out = out_hb @ Wout^T + bout  (bf16 MFMA, fp32 out)
    gemm_bt_mfma<<<dim3(NDIM / 128, NROWS / 128), blk, 0, stream>>>(
        out_hb, Woutb, bout, out, NROWS, NDIM, NDIM);
}

// Round 4
// 379.814 us; speedup vs baseline: 3.7424x; 1.1185x over previous
//
#include <hip/hip_runtime.h>
#include <math.h>

#define NB 8
#define NN 4096
#define NDIM 512
#define NH 8
#define NDH 64
#define QKVC 1536
#define NROWS (NB * NN)
#define EPSF 1e-5f
#define INV_N (1.0f / 4096.0f)
// log2(10000)/16
#define L2_10K_16 0.8304820237218406f

typedef __bf16 bf16x8_t __attribute__((ext_vector_type(8)));
typedef float f32x4_t __attribute__((ext_vector_type(4)));

__device__ inline unsigned short f2bf(float f) {
    unsigned u = __builtin_bit_cast(unsigned, f);
    u += 0x7fff + ((u >> 16) & 1);          // round-to-nearest-even
    return (unsigned short)(u >> 16);
}
__device__ inline float bf2f(unsigned short u) {
    unsigned v = (unsigned)u << 16;
    return __builtin_bit_cast(float, v);
}
__device__ inline float4 bf4_to_f4(ushort4 u) {
    return make_float4(bf2f(u.x), bf2f(u.y), bf2f(u.z), bf2f(u.w));
}

// async global->LDS, 16B per lane; LDS dest = wave-uniform base + lane*16
#define GLOAD_LDS16(g, s) __builtin_amdgcn_global_load_lds(                    \
    (const __attribute__((address_space(1))) void*)(g),                        \
    (__attribute__((address_space(3))) void*)(s), 16, 0, 0)

// ---------------------------------------------------------------------------
// fp32 -> bf16 convert, 8 elems/thread. n must be multiple of 8.
// ---------------------------------------------------------------------------
__global__ __launch_bounds__(256)
void cvt_bf16_kernel(const float* __restrict__ s, unsigned short* __restrict__ d, int n)
{
    const int i = (blockIdx.x * 256 + threadIdx.x) * 8;
    if (i >= n) return;
    float4 a = *(const float4*)(s + i);
    float4 b = *(const float4*)(s + i + 4);
    ushort4 lo, hi;
    lo.x = f2bf(a.x); lo.y = f2bf(a.y); lo.z = f2bf(a.z); lo.w = f2bf(a.w);
    hi.x = f2bf(b.x); hi.y = f2bf(b.y); hi.z = f2bf(b.z); hi.w = f2bf(b.w);
    *(ushort4*)(d + i)     = lo;
    *(ushort4*)(d + i + 4) = hi;
}

// ---------------------------------------------------------------------------
// Fused QKV GEMM: qkvb[m][n] = bf16( post(x[m,:] . Wqkv[n,:]) ), n in [0,1536)
// post = identity+RoPE (q cols), LN+RoPE (k cols), LN (v cols).
// 128x128 tile, BK=32, 4 waves, 4x4 grid of 16x16x32 bf16 MFMAs per wave.
// Each wave's 64x64 quadrant = one full head (64 dims) x 64 rows, so LN and
// RoPE are wave-local: LN = in-lane j-sum + shfl_xor(1,2,4,8) over the 16-col
// group; RoPE pair (d, d+16) = same lane, adjacent j register.
// C/D layout (m89/m91): col = lane&15, row = (lane>>4)*4 + reg.
// ---------------------------------------------------------------------------
__global__ __launch_bounds__(256)
void gemm_qkv_fused(const unsigned short* __restrict__ A,
                    const unsigned short* __restrict__ Bm,
                    const float* __restrict__ pos,
                    const float* __restrict__ gk, const float* __restrict__ bk,
                    const float* __restrict__ gv, const float* __restrict__ bvv,
                    unsigned short* __restrict__ qkvb)
{
    __shared__ unsigned short As[128 * 32];
    __shared__ unsigned short Bs[128 * 32];
    const int t    = threadIdx.x;
    const int wave = t >> 6;
    const int lane = t & 63;
    const int m0 = blockIdx.y * 128;
    const int n0 = blockIdx.x * 128;
    const int wm = (wave >> 1) * 64;
    const int wn = (wave & 1) * 64;
    const int K = NDIM;

    f32x4_t acc[4][4] = {};

    const int srow = wave * 32 + (lane >> 2);
    const int scol = (lane & 3) * 8;
    const unsigned short* Ag = A + (size_t)(m0 + srow) * K + scol;
    const unsigned short* Bg = Bm + (size_t)(n0 + srow) * K + scol;
    unsigned short* sA = As + wave * 1024;
    unsigned short* sB = Bs + wave * 1024;

    const int fr = lane & 15;
    const int fq = (lane >> 4) * 8;

    for (int kt = 0; kt < K; kt += 32) {
        __syncthreads();
        GLOAD_LDS16(Ag + kt,          sA);
        GLOAD_LDS16(Ag + kt + 16 * K, sA + 512);
        GLOAD_LDS16(Bg + kt,          sB);
        GLOAD_LDS16(Bg + kt + 16 * K, sB + 512);
        __syncthreads();

        bf16x8_t af[4], bf[4];
        #pragma unroll
        for (int i = 0; i < 4; ++i) {
            af[i] = *(const bf16x8_t*)&As[(wm + i * 16 + fr) * 32 + fq];
            bf[i] = *(const bf16x8_t*)&Bs[(wn + i * 16 + fr) * 32 + fq];
        }
        #pragma unroll
        for (int i = 0; i < 4; ++i)
            #pragma unroll
            for (int j = 0; j < 4; ++j)
                acc[i][j] = __builtin_amdgcn_mfma_f32_16x16x32_bf16(
                    af[i], bf[j], acc[i][j], 0, 0, 0);
    }

    // ---- fused epilogue ----
    const int type = blockIdx.x >> 2;   // 0=q, 1=k, 2=v  (grid.x = 12)
    const int c  = lane & 15;           // head-dim index mod 16 (= freq idx)
    const int g4 = (lane >> 4) * 4;

    if (type != 0) {                    // LN over head dim (k or v)
        const float* gamma = (type == 1) ? gk : gv;
        const float* beta  = (type == 1) ? bk : bvv;
        float gm[4], bt[4];
        #pragma unroll
        for (int j = 0; j < 4; ++j) { gm[j] = gamma[j * 16 + c]; bt[j] = beta[j * 16 + c]; }
        #pragma unroll
        for (int i = 0; i < 4; ++i)
            #pragma unroll
            for (int r = 0; r < 4; ++r) {
                float t0 = acc[i][0][r], t1 = acc[i][1][r];
                float t2 = acc[i][2][r], t3 = acc[i][3][r];
                float s  = t0 + t1 + t2 + t3;
                float ss = t0*t0 + t1*t1 + t2*t2 + t3*t3;
                #pragma unroll
                for (int msk = 1; msk < 16; msk <<= 1) {
                    s  += __shfl_xor(s,  msk, 64);
                    ss += __shfl_xor(ss, msk, 64);
                }
                const float mu = s * (1.0f / 64.0f);
                const float rs = rsqrtf(ss * (1.0f / 64.0f) - mu * mu + EPSF);
                acc[i][0][r] = (t0 - mu) * rs * gm[0] + bt[0];
                acc[i][1][r] = (t1 - mu) * rs * gm[1] + bt[1];
                acc[i][2][r] = (t2 - mu) * rs * gm[2] + bt[2];
                acc[i][3][r] = (t3 - mu) * rs * gm[3] + bt[3];
            }
    }
    if (type != 2) {                    // RoPE 2D (q or k)
        const float Kc = 64.0f * exp2f(-(float)c * L2_10K_16);
        #pragma unroll
        for (int i = 0; i < 4; ++i)
            #pragma unroll
            for (int r = 0; r < 4; ++r) {
                const int row = m0 + wm + i * 16 + g4 + r;
                const float2 p = ((const float2*)pos)[row];
                float sx, cx, sy, cy;
                __sincosf(p.x * Kc, &sx, &cx);
                __sincosf(p.y * Kc, &sy, &cy);
                const float t0 = acc[i][0][r], t1 = acc[i][1][r];
                const float t2 = acc[i][2][r], t3 = acc[i][3][r];
                acc[i][0][r] = t0 * cx - t1 * sx;
                acc[i][1][r] = t1 * cx + t0 * sx;
                acc[i][2][r] = t2 * cy - t3 * sy;
                acc[i][3][r] = t3 * cy + t2 * sy;
            }
    }
    #pragma unroll
    for (int i = 0; i < 4; ++i)
        #pragma unroll
        for (int j = 0; j < 4; ++j) {
            unsigned short* qp = qkvb + (size_t)(m0 + wm + i * 16 + g4) * QKVC
                               + n0 + wn + j * 16 + c;
            #pragma unroll
            for (int r = 0; r < 4; ++r)
                qp[(size_t)r * QKVC] = f2bf(acc[i][j][r]);
        }
}

// ---------------------------------------------------------------------------
// MFMA GEMM (fp32 C + bias): C[m][n] = sum_k A[m][k]*Bm[n][k] + bias[n]
// ---------------------------------------------------------------------------
__global__ __launch_bounds__(256)
void gemm_bt_mfma(const unsigned short* __restrict__ A,
                  const unsigned short* __restrict__ Bm,
                  const float* __restrict__ bias, float* __restrict__ C,
                  int M, int Nc, int K)
{
    __shared__ unsigned short As[128 * 32];
    __shared__ unsigned short Bs[128 * 32];
    const int t    = threadIdx.x;
    const int wave = t >> 6;
    const int lane = t & 63;
    const int m0 = blockIdx.y * 128;
    const int n0 = blockIdx.x * 128;
    const int wm = (wave >> 1) * 64;
    const int wn = (wave & 1) * 64;

    f32x4_t acc[4][4] = {};

    const int srow = wave * 32 + (lane >> 2);
    const int scol = (lane & 3) * 8;
    const unsigned short* Ag = A + (size_t)(m0 + srow) * K + scol;
    const unsigned short* Bg = Bm + (size_t)(n0 + srow) * K + scol;
    unsigned short* sA = As + wave * 1024;
    unsigned short* sB = Bs + wave * 1024;

    const int fr = lane & 15;
    const int fq = (lane >> 4) * 8;

    for (int kt = 0; kt < K; kt += 32) {
        __syncthreads();
        GLOAD_LDS16(Ag + kt,          sA);
        GLOAD_LDS16(Ag + kt + 16 * K, sA + 512);
        GLOAD_LDS16(Bg + kt,          sB);
        GLOAD_LDS16(Bg + kt + 16 * K, sB + 512);
        __syncthreads();

        bf16x8_t af[4], bf[4];
        #pragma unroll
        for (int i = 0; i < 4; ++i) {
            af[i] = *(const bf16x8_t*)&As[(wm + i * 16 + fr) * 32 + fq];
            bf[i] = *(const bf16x8_t*)&Bs[(wn + i * 16 + fr) * 32 + fq];
        }
        #pragma unroll
        for (int i = 0; i < 4; ++i)
            #pragma unroll
            for (int j = 0; j < 4; ++j)
                acc[i][j] = __builtin_amdgcn_mfma_f32_16x16x32_bf16(
                    af[i], bf[j], acc[i][j], 0, 0, 0);
    }

    const int crow = (lane >> 4) * 4;
    const int ccol = lane & 15;
    #pragma unroll
    for (int j = 0; j < 4; ++j) {
        const int cn = n0 + wn + j * 16 + ccol;
        const float bb = bias ? bias[cn] : 0.0f;
        #pragma unroll
        for (int i = 0; i < 4; ++i) {
            float* cp = C + (size_t)(m0 + wm + i * 16 + crow) * Nc + cn;
            #pragma unroll
            for (int r = 0; r < 4; ++r)
                cp[(size_t)r * Nc] = acc[i][j][r] + bb;
        }
    }
}

// ---------------------------------------------------------------------------
// dots[b][h][d][e] = sum_n k[b,h,n,d] * v[b,h,n,e]  (bf16 in, fp32 atomics)
// ---------------------------------------------------------------------------
__global__ __launch_bounds__(256)
void dots_kernel(const unsigned short* __restrict__ qkvb, float* __restrict__ dots)
{
    __shared__ float ks[8][64];
    __shared__ float vs[8][64];
    const int b = blockIdx.z, h = blockIdx.y;
    const int n0 = blockIdx.x * 256;
    const int t = threadIdx.x;
    const int half = t >> 7;           // 0: load k, 1: load v
    const int idx  = t & 127;
    const int lr = idx >> 4, lq4 = idx & 15;
    const int d0 = (t >> 4) * 4;
    const int e0 = (t & 15) * 4;

    float acc[4][4] = {{0.0f}};
    const size_t gbase = (size_t)(b * NN + n0) * QKVC + (half ? 1024 : 512)
                       + h * NDH + lq4 * 4;

    ushort4 uval = *(const ushort4*)(qkvb + gbase + (size_t)lr * QKVC);
    for (int s = 0; s < 32; ++s) {
        __syncthreads();
        float (*dst)[64] = half ? vs : ks;
        *(float4*)&dst[lr][lq4 * 4] = bf4_to_f4(uval);
        __syncthreads();
        if (s + 1 < 32)
            uval = *(const ushort4*)(qkvb + gbase + (size_t)((s + 1) * 8 + lr) * QKVC);
        #pragma unroll
        for (int r = 0; r < 8; ++r) {
            float4 kd = *(float4*)&ks[r][d0];
            float4 ve = *(float4*)&vs[r][e0];
            acc[0][0] += kd.x*ve.x; acc[0][1] += kd.x*ve.y; acc[0][2] += kd.x*ve.z; acc[0][3] += kd.x*ve.w;
            acc[1][0] += kd.y*ve.x; acc[1][1] += kd.y*ve.y; acc[1][2] += kd.y*ve.z; acc[1][3] += kd.y*ve.w;
            acc[2][0] += kd.z*ve.x; acc[2][1] += kd.z*ve.y; acc[2][2] += kd.z*ve.z; acc[2][3] += kd.z*ve.w;
            acc[3][0] += kd.w*ve.x; acc[3][1] += kd.w*ve.y; acc[3][2] += kd.w*ve.z; acc[3][3] += kd.w*ve.w;
        }
    }
    float* dp = dots + ((size_t)(b * NH + h) * 64 + d0) * 64 + e0;
    #pragma unroll
    for (int i = 0; i < 4; ++i)
        #pragma unroll
        for (int j = 0; j < 4; ++j)
            atomicAdd(dp + i * 64 + j, acc[i][j]);
}

// ---------------------------------------------------------------------------
// out_hb[b][n][h*64+e] = bf16( (1/N) * sum_d q[b,n,h,d] * dots[b][h][d][e] )
// ---------------------------------------------------------------------------
__global__ __launch_bounds__(256)
void qdots_kernel(const unsigned short* __restrict__ qkvb,
                  const float* __restrict__ dots,
                  unsigned short* __restrict__ out_hb)
{
    __shared__ float ds[64][64];
    __shared__ float qs[128][65];
    const int b = blockIdx.z, h = blockIdx.y;
    const int n0 = blockIdx.x * 128;
    const int t = threadIdx.x;

    const float4* dsrc = (const float4*)(dots + (size_t)(b * NH + h) * 4096);
    float4* ddst = (float4*)&ds[0][0];
    #pragma unroll
    for (int i = 0; i < 4; ++i)
        ddst[t + i * 256] = dsrc[t + i * 256];

    #pragma unroll
    for (int i = 0; i < 8; ++i) {
        const int idx = i * 256 + t;
        const int r = idx >> 4, q4 = idx & 15;
        ushort4 qu = *(const ushort4*)(qkvb + (size_t)(b * NN + n0 + r) * QKVC + h * NDH + q4 * 4);
        float4 qv = bf4_to_f4(qu);
        qs[r][q4 * 4 + 0] = qv.x; qs[r][q4 * 4 + 1] = qv.y;
        qs[r][q4 * 4 + 2] = qv.z; qs[r][q4 * 4 + 3] = qv.w;
    }
    __syncthreads();

    const int eq = t & 15;
    const int rg = t >> 4;
    float acc[8][4] = {{0.0f}};
    for (int d = 0; d < 64; ++d) {
        float4 dv = *(float4*)&ds[d][eq * 4];
        #pragma unroll
        for (int r = 0; r < 8; ++r) {
            const float qv = qs[rg * 8 + r][d];
            acc[r][0] += qv * dv.x; acc[r][1] += qv * dv.y;
            acc[r][2] += qv * dv.z; acc[r][3] += qv * dv.w;
        }
    }
    #pragma unroll
    for (int r = 0; r < 8; ++r) {
        ushort4 o;
        o.x = f2bf(acc[r][0] * INV_N); o.y = f2bf(acc[r][1] * INV_N);
        o.z = f2bf(acc[r][2] * INV_N); o.w = f2bf(acc[r][3] * INV_N);
        *(ushort4*)(out_hb + (size_t)(b * NN + n0 + rg * 8 + r) * NDIM + h * NDH + eq * 4) = o;
    }
}

// ---------------------------------------------------------------------------
extern "C" void kernel_launch(void* const* d_in, const int* in_sizes, int n_in,
                              void* d_out, int out_size, void* d_ws, size_t ws_size,
                              hipStream_t stream)
{
    const float* x    = (const float*)d_in[0];
    const float* pos  = (const float*)d_in[1];
    const float* Wqkv = (const float*)d_in[2];
    const float* gk   = (const float*)d_in[3];
    const float* bk   = (const float*)d_in[4];
    const float* gv   = (const float*)d_in[5];
    const float* bv   = (const float*)d_in[6];
    const float* Wout = (const float*)d_in[7];
    const float* bout = (const float*)d_in[8];
    float* out = (float*)d_out;

    // ws: dots(1MiB) | qkvb bf16(96MiB) | xb/out_hb shared(32MiB) | Wb(2MiB)
    float* dots = (float*)d_ws;
    unsigned short* qkvb   = (unsigned short*)(dots + (size_t)NB * NH * 64 * 64);
    unsigned short* xb     = qkvb + (size_t)NROWS * QKVC;
    unsigned short* out_hb = xb;                       // xb dead after QKV GEMM
    unsigned short* Wqkvb  = xb + (size_t)NROWS * NDIM;
    unsigned short* Woutb  = Wqkvb + (size_t)QKVC * NDIM;

    hipMemsetAsync(dots, 0, (size_t)NB * NH * 64 * 64 * sizeof(float), stream);

    dim3 blk(256);
    // 0) fp32 -> bf16 converts
    cvt_bf16_kernel<<<dim3(NROWS * NDIM / 2048), blk, 0, stream>>>(x, xb, NROWS * NDIM);
    cvt_bf16_kernel<<<dim3(QKVC * NDIM / 2048), blk, 0, stream>>>(Wqkv, Wqkvb, QKVC * NDIM);
    cvt_bf16_kernel<<<dim3(NDIM * NDIM / 2048), blk, 0, stream>>>(Wout, Woutb, NDIM * NDIM);
    // 1) qkvb = post( x @ Wqkv^T )  -- LN(k,v) + RoPE(q,k) fused, bf16 out
    gemm_qkv_fused<<<dim3(QKVC / 128, NROWS / 128), blk, 0, stream>>>(
        xb, Wqkvb, pos, gk, bk, gv, bv, qkvb);
    // 2) dots = k^T v per (b,h)
    dots_kernel<<<dim3(NN / 256, NH, NB), blk, 0, stream>>>(qkvb, dots);
    // 3) out_hb = bf16(q @ dots / N)
    qdots_kernel<<<dim3(NN / 128, NH, NB), blk, 0, stream>>>(qkvb, dots, out_hb);
    // 4) out = out_hb @ Wout^T + bout  (bf16 MFMA, fp32 out)
    gemm_bt_mfma<<<dim3(NDIM / 128, NROWS / 128), blk, 0, stream>>>(
        out_hb, Woutb, bout, out, NROWS, NDIM, NDIM);
}

// Round 5
// 338.394 us; speedup vs baseline: 4.2005x; 1.1224x over previous
//
#include <hip/hip_runtime.h>
#include <math.h>

#define NB 8
#define NN 4096
#define NDIM 512
#define NH 8
#define NDH 64
#define QKVC 1536
#define NROWS (NB * NN)
#define EPSF 1e-5f
#define INV_N (1.0f / 4096.0f)
// log2(10000)/16
#define L2_10K_16 0.8304820237218406f

typedef __bf16 bf16x8_t __attribute__((ext_vector_type(8)));
typedef float f32x4_t __attribute__((ext_vector_type(4)));
typedef unsigned short u16x8 __attribute__((ext_vector_type(8)));

__device__ inline unsigned short f2bf(float f) {
    unsigned u = __builtin_bit_cast(unsigned, f);
    u += 0x7fff + ((u >> 16) & 1);          // round-to-nearest-even
    return (unsigned short)(u >> 16);
}
__device__ inline float bf2f(unsigned short u) {
    unsigned v = (unsigned)u << 16;
    return __builtin_bit_cast(float, v);
}

// async global->LDS, 16B per lane; LDS dest = wave-uniform base + lane*16
#define GLOAD_LDS16(g, s) __builtin_amdgcn_global_load_lds(                    \
    (const __attribute__((address_space(1))) void*)(g),                        \
    (__attribute__((address_space(3))) void*)(s), 16, 0, 0)

// ---------------------------------------------------------------------------
// fp32 -> bf16 convert, 8 elems/thread. n must be multiple of 8.
// ---------------------------------------------------------------------------
__global__ __launch_bounds__(256)
void cvt_bf16_kernel(const float* __restrict__ s, unsigned short* __restrict__ d, int n)
{
    const int i = (blockIdx.x * 256 + threadIdx.x) * 8;
    if (i >= n) return;
    float4 a = *(const float4*)(s + i);
    float4 b = *(const float4*)(s + i + 4);
    ushort4 lo, hi;
    lo.x = f2bf(a.x); lo.y = f2bf(a.y); lo.z = f2bf(a.z); lo.w = f2bf(a.w);
    hi.x = f2bf(b.x); hi.y = f2bf(b.y); hi.z = f2bf(b.z); hi.w = f2bf(b.w);
    *(ushort4*)(d + i)     = lo;
    *(ushort4*)(d + i + 4) = hi;
}

// fp32 -> bf16 with scale (for dots -> dots_bf * 1/N), 4 elems/thread
__global__ __launch_bounds__(256)
void cvt_dots_kernel(const float* __restrict__ s, unsigned short* __restrict__ d)
{
    const int i = (blockIdx.x * 256 + threadIdx.x) * 4;
    float4 a = *(const float4*)(s + i);
    ushort4 o;
    o.x = f2bf(a.x * INV_N); o.y = f2bf(a.y * INV_N);
    o.z = f2bf(a.z * INV_N); o.w = f2bf(a.w * INV_N);
    *(ushort4*)(d + i) = o;
}

// ---------------------------------------------------------------------------
// Fused QKV GEMM: qkvb[m][n] = bf16( post(x[m,:] . Wqkv[n,:]) ), n in [0,1536)
// post = RoPE (q cols), LN+RoPE (k cols), LN (v cols). See round-4 notes.
// ---------------------------------------------------------------------------
__global__ __launch_bounds__(256)
void gemm_qkv_fused(const unsigned short* __restrict__ A,
                    const unsigned short* __restrict__ Bm,
                    const float* __restrict__ pos,
                    const float* __restrict__ gk, const float* __restrict__ bk,
                    const float* __restrict__ gv, const float* __restrict__ bvv,
                    unsigned short* __restrict__ qkvb)
{
    __shared__ unsigned short As[128 * 32];
    __shared__ unsigned short Bs[128 * 32];
    const int t    = threadIdx.x;
    const int wave = t >> 6;
    const int lane = t & 63;
    const int m0 = blockIdx.y * 128;
    const int n0 = blockIdx.x * 128;
    const int wm = (wave >> 1) * 64;
    const int wn = (wave & 1) * 64;
    const int K = NDIM;

    f32x4_t acc[4][4] = {};

    const int srow = wave * 32 + (lane >> 2);
    const int scol = (lane & 3) * 8;
    const unsigned short* Ag = A + (size_t)(m0 + srow) * K + scol;
    const unsigned short* Bg = Bm + (size_t)(n0 + srow) * K + scol;
    unsigned short* sA = As + wave * 1024;
    unsigned short* sB = Bs + wave * 1024;

    const int fr = lane & 15;
    const int fq = (lane >> 4) * 8;

    for (int kt = 0; kt < K; kt += 32) {
        __syncthreads();
        GLOAD_LDS16(Ag + kt,          sA);
        GLOAD_LDS16(Ag + kt + 16 * K, sA + 512);
        GLOAD_LDS16(Bg + kt,          sB);
        GLOAD_LDS16(Bg + kt + 16 * K, sB + 512);
        __syncthreads();

        bf16x8_t af[4], bf[4];
        #pragma unroll
        for (int i = 0; i < 4; ++i) {
            af[i] = *(const bf16x8_t*)&As[(wm + i * 16 + fr) * 32 + fq];
            bf[i] = *(const bf16x8_t*)&Bs[(wn + i * 16 + fr) * 32 + fq];
        }
        #pragma unroll
        for (int i = 0; i < 4; ++i)
            #pragma unroll
            for (int j = 0; j < 4; ++j)
                acc[i][j] = __builtin_amdgcn_mfma_f32_16x16x32_bf16(
                    af[i], bf[j], acc[i][j], 0, 0, 0);
    }

    // ---- fused epilogue ----
    const int type = blockIdx.x >> 2;   // 0=q, 1=k, 2=v  (grid.x = 12)
    const int c  = lane & 15;
    const int g4 = (lane >> 4) * 4;

    if (type != 0) {                    // LN over head dim (k or v)
        const float* gamma = (type == 1) ? gk : gv;
        const float* beta  = (type == 1) ? bk : bvv;
        float gm[4], bt[4];
        #pragma unroll
        for (int j = 0; j < 4; ++j) { gm[j] = gamma[j * 16 + c]; bt[j] = beta[j * 16 + c]; }
        #pragma unroll
        for (int i = 0; i < 4; ++i)
            #pragma unroll
            for (int r = 0; r < 4; ++r) {
                float t0 = acc[i][0][r], t1 = acc[i][1][r];
                float t2 = acc[i][2][r], t3 = acc[i][3][r];
                float s  = t0 + t1 + t2 + t3;
                float ss = t0*t0 + t1*t1 + t2*t2 + t3*t3;
                #pragma unroll
                for (int msk = 1; msk < 16; msk <<= 1) {
                    s  += __shfl_xor(s,  msk, 64);
                    ss += __shfl_xor(ss, msk, 64);
                }
                const float mu = s * (1.0f / 64.0f);
                const float rs = rsqrtf(ss * (1.0f / 64.0f) - mu * mu + EPSF);
                acc[i][0][r] = (t0 - mu) * rs * gm[0] + bt[0];
                acc[i][1][r] = (t1 - mu) * rs * gm[1] + bt[1];
                acc[i][2][r] = (t2 - mu) * rs * gm[2] + bt[2];
                acc[i][3][r] = (t3 - mu) * rs * gm[3] + bt[3];
            }
    }
    if (type != 2) {                    // RoPE 2D (q or k)
        const float Kc = 64.0f * exp2f(-(float)c * L2_10K_16);
        #pragma unroll
        for (int i = 0; i < 4; ++i)
            #pragma unroll
            for (int r = 0; r < 4; ++r) {
                const int row = m0 + wm + i * 16 + g4 + r;
                const float2 p = ((const float2*)pos)[row];
                float sx, cx, sy, cy;
                __sincosf(p.x * Kc, &sx, &cx);
                __sincosf(p.y * Kc, &sy, &cy);
                const float t0 = acc[i][0][r], t1 = acc[i][1][r];
                const float t2 = acc[i][2][r], t3 = acc[i][3][r];
                acc[i][0][r] = t0 * cx - t1 * sx;
                acc[i][1][r] = t1 * cx + t0 * sx;
                acc[i][2][r] = t2 * cy - t3 * sy;
                acc[i][3][r] = t3 * cy + t2 * sy;
            }
    }
    #pragma unroll
    for (int i = 0; i < 4; ++i)
        #pragma unroll
        for (int j = 0; j < 4; ++j) {
            unsigned short* qp = qkvb + (size_t)(m0 + wm + i * 16 + g4) * QKVC
                               + n0 + wn + j * 16 + c;
            #pragma unroll
            for (int r = 0; r < 4; ++r)
                qp[(size_t)r * QKVC] = f2bf(acc[i][j][r]);
        }
}

// ---------------------------------------------------------------------------
// dots[b][h][d][e] = sum_n k[b,h,n,d] * v[b,h,n,e]  (bf16 in, fp32 atomics)
// 512 blocks: (8 n-chunks of 512, 8 h, 8 b). 32-row fp32 LDS stages, 1-stage
// register prefetch (one u16x8 per operand per thread per stage).
// ---------------------------------------------------------------------------
__global__ __launch_bounds__(256)
void dots_kernel(const unsigned short* __restrict__ qkvb, float* __restrict__ dots)
{
    __shared__ float ks[32][64];
    __shared__ float vs[32][64];
    const int b = blockIdx.z, h = blockIdx.y;
    const int n0 = blockIdx.x * 512;
    const int t = threadIdx.x;
    const int row = t >> 3;            // 0..31
    const int c8  = (t & 7) * 8;
    const int d0 = (t >> 4) * 4;
    const int e0 = (t & 15) * 4;

    float acc[4][4] = {{0.0f}};
    const size_t kbase = (size_t)(b * NN + n0 + row) * QKVC + 512 + h * NDH + c8;
    const size_t vbase = kbase + 512;

    u16x8 ku = *(const u16x8*)(qkvb + kbase);
    u16x8 vu = *(const u16x8*)(qkvb + vbase);

    for (int s = 0; s < 16; ++s) {
        __syncthreads();
        #pragma unroll
        for (int j = 0; j < 8; ++j) {
            ks[row][c8 + j] = bf2f(ku[j]);
            vs[row][c8 + j] = bf2f(vu[j]);
        }
        __syncthreads();
        if (s + 1 < 16) {
            ku = *(const u16x8*)(qkvb + kbase + (size_t)(s + 1) * 32 * QKVC);
            vu = *(const u16x8*)(qkvb + vbase + (size_t)(s + 1) * 32 * QKVC);
        }
        #pragma unroll
        for (int r = 0; r < 32; ++r) {
            float4 kd = *(float4*)&ks[r][d0];
            float4 ve = *(float4*)&vs[r][e0];
            acc[0][0] += kd.x*ve.x; acc[0][1] += kd.x*ve.y; acc[0][2] += kd.x*ve.z; acc[0][3] += kd.x*ve.w;
            acc[1][0] += kd.y*ve.x; acc[1][1] += kd.y*ve.y; acc[1][2] += kd.y*ve.z; acc[1][3] += kd.y*ve.w;
            acc[2][0] += kd.z*ve.x; acc[2][1] += kd.z*ve.y; acc[2][2] += kd.z*ve.z; acc[2][3] += kd.z*ve.w;
            acc[3][0] += kd.w*ve.x; acc[3][1] += kd.w*ve.y; acc[3][2] += kd.w*ve.z; acc[3][3] += kd.w*ve.w;
        }
    }
    float* dp = dots + ((size_t)(b * NH + h) * 64 + d0) * 64 + e0;
    #pragma unroll
    for (int i = 0; i < 4; ++i)
        #pragma unroll
        for (int j = 0; j < 4; ++j)
            atomicAdd(dp + i * 64 + j, acc[i][j]);
}

// ---------------------------------------------------------------------------
// M2b[b][d'][h*64+d] = bf16( sum_e dots_bf[b,h,d,e] * Woutb[d', h*64+e] )
// (dots_bf already carries the 1/N factor.)  Per block: (d'-tile 128, h, b),
// C-tile 128(d') x 64(d), K = 64(e), single K-span, 16 MFMAs per wave.
// ---------------------------------------------------------------------------
__global__ __launch_bounds__(256)
void dotsw_mfma(const unsigned short* __restrict__ Woutb,
                const unsigned short* __restrict__ dots_bf,
                unsigned short* __restrict__ M2b)
{
    __shared__ unsigned short As[128 * 64];   // Wout tile, row-major (16 KB)
    __shared__ unsigned short Bs[64 * 64];    // dots[b,h], row-major (8 KB)
    const int t = threadIdx.x;
    const int wave = t >> 6;
    const int lane = t & 63;
    const int dp0 = blockIdx.x * 128;
    const int h = blockIdx.y, b = blockIdx.z;

    const int srow = lane >> 3;               // 0..7
    const int scol = (lane & 7) * 8;
    const unsigned short* Ag = Woutb + (size_t)(dp0 + wave * 32 + srow) * NDIM
                             + h * NDH + scol;
    const unsigned short* Bg = dots_bf + ((size_t)(b * NH + h) * 64 + wave * 16 + srow) * 64
                             + scol;
    #pragma unroll
    for (int i = 0; i < 4; ++i)
        GLOAD_LDS16(Ag + (size_t)i * 8 * NDIM, As + wave * 2048 + i * 512);
    #pragma unroll
    for (int i = 0; i < 2; ++i)
        GLOAD_LDS16(Bg + (size_t)i * 8 * 64, Bs + wave * 1024 + i * 512);
    __syncthreads();

    const int wm = (wave >> 1) * 64;          // d' quadrant
    const int wn = (wave & 1) * 32;           // d half
    const int fr = lane & 15;
    const int fq = (lane >> 4) * 8;

    f32x4_t acc[4][2] = {};
    #pragma unroll
    for (int kk = 0; kk < 2; ++kk) {
        bf16x8_t af[4], bf[2];
        #pragma unroll
        for (int i = 0; i < 4; ++i)
            af[i] = *(const bf16x8_t*)&As[(wm + i * 16 + fr) * 64 + kk * 32 + fq];
        #pragma unroll
        for (int j = 0; j < 2; ++j)
            bf[j] = *(const bf16x8_t*)&Bs[(wn + j * 16 + fr) * 64 + kk * 32 + fq];
        #pragma unroll
        for (int i = 0; i < 4; ++i)
            #pragma unroll
            for (int j = 0; j < 2; ++j)
                acc[i][j] = __builtin_amdgcn_mfma_f32_16x16x32_bf16(
                    af[i], bf[j], acc[i][j], 0, 0, 0);
    }

    const int c  = lane & 15;
    const int g4 = (lane >> 4) * 4;
    #pragma unroll
    for (int i = 0; i < 4; ++i)
        #pragma unroll
        for (int j = 0; j < 2; ++j) {
            unsigned short* mp = M2b + ((size_t)(b * NDIM) + dp0 + wm + i * 16 + g4) * NDIM
                               + h * NDH + wn + j * 16 + c;
            #pragma unroll
            for (int r = 0; r < 4; ++r)
                mp[(size_t)r * NDIM] = f2bf(acc[i][j][r]);
        }
}

// ---------------------------------------------------------------------------
// out[b*NN+m][d'] = sum_hd q[b,m,hd] * M2b[b][d'][hd] + bout[d']   (fp32 out)
// A = qkvb q-columns (lda = QKVC), B = M2b[b] (ldb = NDIM), K = NDIM.
// ---------------------------------------------------------------------------
__global__ __launch_bounds__(256)
void gemm_out_mfma(const unsigned short* __restrict__ qkvb,
                   const unsigned short* __restrict__ M2b,
                   const float* __restrict__ bias, float* __restrict__ C)
{
    __shared__ unsigned short As[128 * 32];
    __shared__ unsigned short Bs[128 * 32];
    const int t    = threadIdx.x;
    const int wave = t >> 6;
    const int lane = t & 63;
    const int b  = blockIdx.z;
    const int m0 = b * NN + blockIdx.y * 128;
    const int n0 = blockIdx.x * 128;
    const int wm = (wave >> 1) * 64;
    const int wn = (wave & 1) * 64;
    const int K = NDIM;

    f32x4_t acc[4][4] = {};

    const int srow = wave * 32 + (lane >> 2);
    const int scol = (lane & 3) * 8;
    const unsigned short* Ag = qkvb + (size_t)(m0 + srow) * QKVC + scol;
    const unsigned short* Bg = M2b + ((size_t)b * NDIM + n0 + srow) * NDIM + scol;
    unsigned short* sA = As + wave * 1024;
    unsigned short* sB = Bs + wave * 1024;

    const int fr = lane & 15;
    const int fq = (lane >> 4) * 8;

    for (int kt = 0; kt < K; kt += 32) {
        __syncthreads();
        GLOAD_LDS16(Ag + kt,             sA);
        GLOAD_LDS16(Ag + kt + (size_t)16 * QKVC, sA + 512);
        GLOAD_LDS16(Bg + kt,             sB);
        GLOAD_LDS16(Bg + kt + 16 * NDIM, sB + 512);
        __syncthreads();

        bf16x8_t af[4], bf[4];
        #pragma unroll
        for (int i = 0; i < 4; ++i) {
            af[i] = *(const bf16x8_t*)&As[(wm + i * 16 + fr) * 32 + fq];
            bf[i] = *(const bf16x8_t*)&Bs[(wn + i * 16 + fr) * 32 + fq];
        }
        #pragma unroll
        for (int i = 0; i < 4; ++i)
            #pragma unroll
            for (int j = 0; j < 4; ++j)
                acc[i][j] = __builtin_amdgcn_mfma_f32_16x16x32_bf16(
                    af[i], bf[j], acc[i][j], 0, 0, 0);
    }

    const int crow = (lane >> 4) * 4;
    const int ccol = lane & 15;
    #pragma unroll
    for (int j = 0; j < 4; ++j) {
        const int cn = n0 + wn + j * 16 + ccol;
        const float bb = bias[cn];
        #pragma unroll
        for (int i = 0; i < 4; ++i) {
            float* cp = C + (size_t)(m0 + wm + i * 16 + crow) * NDIM + cn;
            #pragma unroll
            for (int r = 0; r < 4; ++r)
                cp[(size_t)r * NDIM] = acc[i][j][r] + bb;
        }
    }
}

// ---------------------------------------------------------------------------
extern "C" void kernel_launch(void* const* d_in, const int* in_sizes, int n_in,
                              void* d_out, int out_size, void* d_ws, size_t ws_size,
                              hipStream_t stream)
{
    const float* x    = (const float*)d_in[0];
    const float* pos  = (const float*)d_in[1];
    const float* Wqkv = (const float*)d_in[2];
    const float* gk   = (const float*)d_in[3];
    const float* bk   = (const float*)d_in[4];
    const float* gv   = (const float*)d_in[5];
    const float* bv   = (const float*)d_in[6];
    const float* Wout = (const float*)d_in[7];
    const float* bout = (const float*)d_in[8];
    float* out = (float*)d_out;

    // ws: dots f32(1M) | dots_bf(0.5M) | M2b(4M) | qkvb(96M) | xb(32M) | W(2M)
    float* dots = (float*)d_ws;
    unsigned short* dots_bf = (unsigned short*)(dots + (size_t)NB * NH * 64 * 64);
    unsigned short* M2b     = dots_bf + (size_t)NB * NH * 64 * 64;
    unsigned short* qkvb    = M2b + (size_t)NB * NDIM * NDIM;
    unsigned short* xb      = qkvb + (size_t)NROWS * QKVC;
    unsigned short* Wqkvb   = xb + (size_t)NROWS * NDIM;
    unsigned short* Woutb   = Wqkvb + (size_t)QKVC * NDIM;

    hipMemsetAsync(dots, 0, (size_t)NB * NH * 64 * 64 * sizeof(float), stream);

    dim3 blk(256);
    // 0) fp32 -> bf16 converts
    cvt_bf16_kernel<<<dim3(NROWS * NDIM / 2048), blk, 0, stream>>>(x, xb, NROWS * NDIM);
    cvt_bf16_kernel<<<dim3(QKVC * NDIM / 2048), blk, 0, stream>>>(Wqkv, Wqkvb, QKVC * NDIM);
    cvt_bf16_kernel<<<dim3(NDIM * NDIM / 2048), blk, 0, stream>>>(Wout, Woutb, NDIM * NDIM);
    // 1) qkvb = post( x @ Wqkv^T )  -- LN(k,v) + RoPE(q,k) fused, bf16 out
    gemm_qkv_fused<<<dim3(QKVC / 128, NROWS / 128), blk, 0, stream>>>(
        xb, Wqkvb, pos, gk, bk, gv, bv, qkvb);
    // 2) dots = k^T v per (b,h)
    dots_kernel<<<dim3(NN / 512, NH, NB), blk, 0, stream>>>(qkvb, dots);
    // 3) dots_bf = bf16(dots / N)
    cvt_dots_kernel<<<dim3(NB * NH * 64 * 64 / 1024), blk, 0, stream>>>(dots, dots_bf);
    // 4) M2b[b] = (dots_bf[b] @ blockdiag) x Wout^T  (bf16 MFMA)
    dotsw_mfma<<<dim3(NDIM / 128, NH, NB), blk, 0, stream>>>(Woutb, dots_bf, M2b);
    // 5) out = q @ M2b[b]^T + bout  (bf16 MFMA, fp32 out)
    gemm_out_mfma<<<dim3(NDIM / 128, NN / 128, NB), blk, 0, stream>>>(
        qkvb, M2b, bout, out);
}